// Round 1
// baseline (880.595 us; speedup 1.0000x reference)
//
#include <hip/hip_runtime.h>

#define RNN_B 256
#define RNN_T 2048
#define RNN_IN 64
#define RNN_N 32
#define RNN_O 32
#define RNN_R 6
#define RNN_ALPHA 0.1f

// ---------------------------------------------------------------------------
// Kernel 1: xp[b][t][n] = bias[n] + sum_i W_in[n][i] * u[b][t][i]
// Written into d_out[(b*T+t)*32 + n] (later overwritten in place by h, then y).
// Thread per (b,t): reads its own contiguous 256 B of u, writes its own 128 B line.
// ---------------------------------------------------------------------------
__global__ __launch_bounds__(256) void k_xproj(
    const float* __restrict__ u, const float* __restrict__ W_in,
    const float* __restrict__ bias, float* __restrict__ xp)
{
    const int tid = blockIdx.x * 256 + threadIdx.x;   // = b*T + t
    const float4* __restrict__ u4 =
        reinterpret_cast<const float4*>(u) + (size_t)tid * (RNN_IN / 4);
    float uu[RNN_IN];
    #pragma unroll
    for (int q = 0; q < RNN_IN / 4; ++q) {
        float4 v = u4[q];
        uu[4*q+0] = v.x; uu[4*q+1] = v.y; uu[4*q+2] = v.z; uu[4*q+3] = v.w;
    }
    float acc[RNN_N];
    #pragma unroll
    for (int n = 0; n < RNN_N; ++n) acc[n] = bias[n];
    #pragma unroll
    for (int i = 0; i < RNN_IN; ++i) {
        const float ui = uu[i];
        #pragma unroll
        for (int n = 0; n < RNN_N; ++n)
            acc[n] = fmaf(W_in[n * RNN_IN + i], ui, acc[n]);  // W_in uniform -> s_load
    }
    float4* __restrict__ o4 =
        reinterpret_cast<float4*>(xp) + (size_t)tid * (RNN_N / 4);
    #pragma unroll
    for (int q = 0; q < RNN_N / 4; ++q)
        o4[q] = make_float4(acc[4*q+0], acc[4*q+1], acc[4*q+2], acc[4*q+3]);
}

// ---------------------------------------------------------------------------
// Kernel 2: the sequential scan. One wave (64 threads) per batch element.
// Lane n (n = lane&31) owns h[n]; upper half replicates (harmless, masked on
// stores). Per step: broadcast h via v_readlane -> 32 fma against the W_rec
// row held in 32 VGPRs; fast tanh; leak update. x is read from d_out and the
// same 128-B line is overwritten with h (in place, same-thread ordering).
// ---------------------------------------------------------------------------
__global__ __launch_bounds__(64) void k_recur(
    const float* __restrict__ m, const float* __restrict__ nvec,
    const float* __restrict__ Mmat, const float* __restrict__ Nmat,
    float* __restrict__ dout, float* __restrict__ hfin)
{
    const int b    = blockIdx.x;
    const int lane = threadIdx.x;
    const int n1   = lane & (RNN_N - 1);

    // Build W_rec row n1: W[n1][k] = m[n1]*n[k] + sum_r M[n1][r]*N[k][r]
    float Mr[RNN_R];
    const float mn = m[n1];
    #pragma unroll
    for (int r = 0; r < RNN_R; ++r) Mr[r] = Mmat[n1 * RNN_R + r];
    float Wrow[RNN_N];
    #pragma unroll
    for (int k = 0; k < RNN_N; ++k) {
        float w = mn * nvec[k];                    // nvec/Nmat uniform -> s_load
        #pragma unroll
        for (int r = 0; r < RNN_R; ++r) w = fmaf(Mr[r], Nmat[k * RNN_R + r], w);
        Wrow[k] = w;
    }

    float* __restrict__ base = dout + (size_t)b * (RNN_T * RNN_N);
    float h = 0.0f;

    const int PF = 4;                              // prefetch depth (~600 cyc cover)
    float xr[PF];
    #pragma unroll
    for (int i = 0; i < PF; ++i) xr[i] = base[i * RNN_N + n1];

    #pragma unroll 4
    for (int t = 0; t < RNN_T; ++t) {
        const float xc = xr[0];
        xr[0] = xr[1]; xr[1] = xr[2]; xr[2] = xr[3];
        if (t + PF < RNN_T) xr[PF - 1] = base[(t + PF) * RNN_N + n1];

        float a0 = xc, a1 = 0.f, a2 = 0.f, a3 = 0.f;
        const int hb = __float_as_int(h);
        #pragma unroll
        for (int k = 0; k < RNN_N; k += 4) {
            const float h0 = __int_as_float(__builtin_amdgcn_readlane(hb, k + 0));
            const float h1 = __int_as_float(__builtin_amdgcn_readlane(hb, k + 1));
            const float h2 = __int_as_float(__builtin_amdgcn_readlane(hb, k + 2));
            const float h3 = __int_as_float(__builtin_amdgcn_readlane(hb, k + 3));
            a0 = fmaf(Wrow[k + 0], h0, a0);
            a1 = fmaf(Wrow[k + 1], h1, a1);
            a2 = fmaf(Wrow[k + 2], h2, a2);
            a3 = fmaf(Wrow[k + 3], h3, a3);
        }
        const float pre = (a0 + a1) + (a2 + a3);

        // tanh(p) = 1 - 2/(exp(2p)+1); |pre| <~ 5 so no overflow.
        const float e  = __expf(2.0f * pre);
        const float th = 1.0f - __fdividef(2.0f, e + 1.0f);
        h = fmaf(RNN_ALPHA, th - h, h);            // (1-a)h + a*tanh

        if (lane < RNN_N) base[t * RNN_N + n1] = h;
    }
    if (lane < RNN_N) hfin[b * RNN_N + n1] = h;
}

// ---------------------------------------------------------------------------
// Kernel 3: in-place output projection. Thread per (b,t): reads its 32-float
// h line from d_out, writes y = W_out h + b_out back to the same line.
// ---------------------------------------------------------------------------
__global__ __launch_bounds__(256) void k_out(
    const float* __restrict__ W_out, const float* __restrict__ b_out,
    float* __restrict__ dout)
{
    const int tid = blockIdx.x * 256 + threadIdx.x;   // = b*T + t
    float4* __restrict__ p4 =
        reinterpret_cast<float4*>(dout) + (size_t)tid * (RNN_N / 4);
    float hv[RNN_N];
    #pragma unroll
    for (int q = 0; q < RNN_N / 4; ++q) {
        float4 v = p4[q];
        hv[4*q+0] = v.x; hv[4*q+1] = v.y; hv[4*q+2] = v.z; hv[4*q+3] = v.w;
    }
    float y[RNN_O];
    #pragma unroll
    for (int o = 0; o < RNN_O; ++o) y[o] = b_out[o];
    #pragma unroll
    for (int n = 0; n < RNN_N; ++n) {
        const float hn = hv[n];
        #pragma unroll
        for (int o = 0; o < RNN_O; ++o)
            y[o] = fmaf(W_out[o * RNN_N + n], hn, y[o]);  // uniform -> s_load
    }
    #pragma unroll
    for (int q = 0; q < RNN_N / 4; ++q)
        p4[q] = make_float4(y[4*q+0], y[4*q+1], y[4*q+2], y[4*q+3]);
}

extern "C" void kernel_launch(void* const* d_in, const int* in_sizes, int n_in,
                              void* d_out, int out_size, void* d_ws, size_t ws_size,
                              hipStream_t stream)
{
    const float* u     = (const float*)d_in[0];  // [256,2048,64]
    const float* W_in  = (const float*)d_in[1];  // [32,64]
    const float* m     = (const float*)d_in[2];  // [32,1]
    const float* nvec  = (const float*)d_in[3];  // [32,1]
    const float* Mmat  = (const float*)d_in[4];  // [32,6]
    const float* Nmat  = (const float*)d_in[5];  // [32,6]
    const float* bias  = (const float*)d_in[6];  // [32]
    const float* W_out = (const float*)d_in[7];  // [32,32]
    const float* b_out = (const float*)d_in[8];  // [32]
    float* out = (float*)d_out;                  // outputs [256,2048,32] ++ h_final [256,32]

    float* hfin = out + (size_t)RNN_B * RNN_T * RNN_N;

    k_xproj<<<(RNN_B * RNN_T) / 256, 256, 0, stream>>>(u, W_in, bias, out);
    k_recur<<<RNN_B, 64, 0, stream>>>(m, nvec, Mmat, Nmat, out, hfin);
    k_out  <<<(RNN_B * RNN_T) / 256, 256, 0, stream>>>(W_out, b_out, out);
}

// Round 2
// 792.617 us; speedup vs baseline: 1.1110x; 1.1110x over previous
//
#include <hip/hip_runtime.h>

#define RNN_B 256
#define RNN_T 2048
#define RNN_IN 64
#define RNN_N 32
#define RNN_O 32
#define RNN_R 6
#define RNN_ALPHA 0.1f

// ---------------------------------------------------------------------------
// Kernel 1: xp[b][t][n] = bias[n] + sum_i W_in[n][i] * u[b][t][i]
// Written into d_out[(b*T+t)*32 + n] (later overwritten in place by h, then y).
// ---------------------------------------------------------------------------
__global__ __launch_bounds__(256) void k_xproj(
    const float* __restrict__ u, const float* __restrict__ W_in,
    const float* __restrict__ bias, float* __restrict__ xp)
{
    const int tid = blockIdx.x * 256 + threadIdx.x;   // = b*T + t
    const float4* __restrict__ u4 =
        reinterpret_cast<const float4*>(u) + (size_t)tid * (RNN_IN / 4);
    float uu[RNN_IN];
    #pragma unroll
    for (int q = 0; q < RNN_IN / 4; ++q) {
        float4 v = u4[q];
        uu[4*q+0] = v.x; uu[4*q+1] = v.y; uu[4*q+2] = v.z; uu[4*q+3] = v.w;
    }
    float acc[RNN_N];
    #pragma unroll
    for (int n = 0; n < RNN_N; ++n) acc[n] = bias[n];
    #pragma unroll
    for (int i = 0; i < RNN_IN; ++i) {
        const float ui = uu[i];
        #pragma unroll
        for (int n = 0; n < RNN_N; ++n)
            acc[n] = fmaf(W_in[n * RNN_IN + i], ui, acc[n]);  // W_in uniform -> s_load
    }
    float4* __restrict__ o4 =
        reinterpret_cast<float4*>(xp) + (size_t)tid * (RNN_N / 4);
    #pragma unroll
    for (int q = 0; q < RNN_N / 4; ++q)
        o4[q] = make_float4(acc[4*q+0], acc[4*q+1], acc[4*q+2], acc[4*q+3]);
}

// ---------------------------------------------------------------------------
// 32-lane all-reduce sum (both 32-halves of the wave reduce independently;
// we replicate the batch across halves so both get the same answer).
// Stage order: xor16 (ds_swizzle, long latency — issue first so the 7
// independent chains pipeline through the LDS pipe), then 4 DPP stages on
// the VALU pipe. Every lane ends with the full 32-sum.
// ---------------------------------------------------------------------------
template <int CTRL>
__device__ __forceinline__ float dpp_add(float v) {
    int t = __builtin_amdgcn_update_dpp(0, __float_as_int(v), CTRL, 0xf, 0xf, true);
    return v + __int_as_float(t);
}

__device__ __forceinline__ float sum32(float v) {
    // BitMode swizzle: offset = (xor<<10)|(or<<5)|and ; xor=16, and=31 -> 0x401F
    v += __int_as_float(__builtin_amdgcn_ds_swizzle(__float_as_int(v), 0x401F));
    v = dpp_add<0xB1>(v);    // quad_perm [1,0,3,2]  : xor 1
    v = dpp_add<0x4E>(v);    // quad_perm [2,3,0,1]  : xor 2
    v = dpp_add<0x141>(v);   // row_half_mirror      : cross-quad within 8
    v = dpp_add<0x140>(v);   // row_mirror           : cross-8 within 16
    return v;
}

// ---------------------------------------------------------------------------
// Kernel 2: sequential scan, one wave per batch, lane k owns h[k] (upper
// 32 lanes replicate). Rank-7 trick: W_rec = m n^T + M N^T, so
//   pre[n] = x[n] + m[n]*(n.h) + sum_r M[n][r]*(N[:,r].h)
// = 7 per-lane products, 7 cross-lane sum32 reductions, 7 FMAs. No dense
// 32x32 matvec, no readlane broadcast, ~25 live VGPRs (no spill).
// ---------------------------------------------------------------------------
__global__ __launch_bounds__(64, 1) void k_recur(
    const float* __restrict__ m, const float* __restrict__ nvec,
    const float* __restrict__ Mmat, const float* __restrict__ Nmat,
    float* __restrict__ dout, float* __restrict__ hfin)
{
    const int b    = blockIdx.x;
    const int lane = threadIdx.x;
    const int k    = lane & (RNN_N - 1);   // h index owned; also output row n

    // Right factors (applied to local h before reduction):
    float cN[RNN_R + 1];
    cN[0] = nvec[k];
    #pragma unroll
    for (int r = 0; r < RNN_R; ++r) cN[r + 1] = Nmat[k * RNN_R + r];
    // Left factors (applied to the broadcast sums):
    float cM[RNN_R + 1];
    cM[0] = m[k];
    #pragma unroll
    for (int r = 0; r < RNN_R; ++r) cM[r + 1] = Mmat[k * RNN_R + r];

    float* __restrict__ base = dout + (size_t)b * (RNN_T * RNN_N);
    float h = 0.0f;

    const int PF = 4;                       // prefetch depth
    float xr[PF];
    #pragma unroll
    for (int i = 0; i < PF; ++i) xr[i] = base[i * RNN_N + k];

    #pragma unroll 4
    for (int t = 0; t < RNN_T; ++t) {
        const float xc = xr[0];
        xr[0] = xr[1]; xr[1] = xr[2]; xr[2] = xr[3];
        // Unconditional prefetch: for t+PF >= T this reads into the next
        // batch's region / the h_final area — both allocated; value unused.
        xr[PF - 1] = base[(t + PF) * RNN_N + k];

        // 7 products, 7 independent all-reduce chains (scheduler interleaves).
        float s[RNN_R + 1];
        #pragma unroll
        for (int r = 0; r < RNN_R + 1; ++r) s[r] = sum32(h * cN[r]);

        // pre = xc + sum_r cM[r]*s[r]  (two FMA chains for shorter dep path)
        float p0 = fmaf(cM[0], s[0], xc);
        float p1 = cM[1] * s[1];
        p0 = fmaf(cM[2], s[2], p0);
        p1 = fmaf(cM[3], s[3], p1);
        p0 = fmaf(cM[4], s[4], p0);
        p1 = fmaf(cM[5], s[5], p1);
        p0 = fmaf(cM[6], s[6], p0);
        const float pre = p0 + p1;

        // tanh(p) = 1 - 2/(exp(2p)+1)
        const float e  = __expf(2.0f * pre);
        const float th = 1.0f - __fdividef(2.0f, e + 1.0f);
        h = fmaf(RNN_ALPHA, th - h, h);     // (1-a)h + a*tanh

        if (lane < RNN_N) base[t * RNN_N + k] = h;
    }
    if (lane < RNN_N) hfin[b * RNN_N + k] = h;
}

// ---------------------------------------------------------------------------
// Kernel 3: in-place output projection. Thread per (b,t): reads its 32-float
// h line from d_out, writes y = W_out h + b_out back to the same line.
// ---------------------------------------------------------------------------
__global__ __launch_bounds__(256) void k_out(
    const float* __restrict__ W_out, const float* __restrict__ b_out,
    float* __restrict__ dout)
{
    const int tid = blockIdx.x * 256 + threadIdx.x;   // = b*T + t
    float4* __restrict__ p4 =
        reinterpret_cast<float4*>(dout) + (size_t)tid * (RNN_N / 4);
    float hv[RNN_N];
    #pragma unroll
    for (int q = 0; q < RNN_N / 4; ++q) {
        float4 v = p4[q];
        hv[4*q+0] = v.x; hv[4*q+1] = v.y; hv[4*q+2] = v.z; hv[4*q+3] = v.w;
    }
    float y[RNN_O];
    #pragma unroll
    for (int o = 0; o < RNN_O; ++o) y[o] = b_out[o];
    #pragma unroll
    for (int n = 0; n < RNN_N; ++n) {
        const float hn = hv[n];
        #pragma unroll
        for (int o = 0; o < RNN_O; ++o)
            y[o] = fmaf(W_out[o * RNN_N + n], hn, y[o]);  // uniform -> s_load
    }
    #pragma unroll
    for (int q = 0; q < RNN_N / 4; ++q)
        p4[q] = make_float4(y[4*q+0], y[4*q+1], y[4*q+2], y[4*q+3]);
}

extern "C" void kernel_launch(void* const* d_in, const int* in_sizes, int n_in,
                              void* d_out, int out_size, void* d_ws, size_t ws_size,
                              hipStream_t stream)
{
    const float* u     = (const float*)d_in[0];  // [256,2048,64]
    const float* W_in  = (const float*)d_in[1];  // [32,64]
    const float* m     = (const float*)d_in[2];  // [32,1]
    const float* nvec  = (const float*)d_in[3];  // [32,1]
    const float* Mmat  = (const float*)d_in[4];  // [32,6]
    const float* Nmat  = (const float*)d_in[5];  // [32,6]
    const float* bias  = (const float*)d_in[6];  // [32]
    const float* W_out = (const float*)d_in[7];  // [32,32]
    const float* b_out = (const float*)d_in[8];  // [32]
    float* out = (float*)d_out;                  // outputs [256,2048,32] ++ h_final [256,32]

    float* hfin = out + (size_t)RNN_B * RNN_T * RNN_N;

    k_xproj<<<(RNN_B * RNN_T) / 256, 256, 0, stream>>>(u, W_in, bias, out);
    k_recur<<<RNN_B, 64, 0, stream>>>(m, nvec, Mmat, Nmat, out, hfin);
    k_out  <<<(RNN_B * RNN_T) / 256, 256, 0, stream>>>(W_out, b_out, out);
}

// Round 3
// 742.154 us; speedup vs baseline: 1.1865x; 1.0680x over previous
//
#include <hip/hip_runtime.h>

#define RNN_B 256
#define RNN_T 2048
#define RNN_IN 64
#define RNN_N 32
#define RNN_O 32
#define RNN_R 6
#define RNN_ALPHA 0.1f
#define KSCALE 2.8853900817779268f   /* 2*log2(e): folded into cM and x */

// ---------------------------------------------------------------------------
// Kernel 1: xp[b][t][n] = bias[n] + sum_i W_in[n][i] * u[b][t][i]
// into d_out. i-loop chunked by 4 so live regs ~45 (no spill).
// ---------------------------------------------------------------------------
__global__ __launch_bounds__(256) void k_xproj(
    const float* __restrict__ u, const float* __restrict__ W_in,
    const float* __restrict__ bias, float* __restrict__ xp)
{
    const int tid = blockIdx.x * 256 + threadIdx.x;   // = b*T + t
    const float4* __restrict__ u4 =
        reinterpret_cast<const float4*>(u) + (size_t)tid * (RNN_IN / 4);
    float acc[RNN_N];
    #pragma unroll
    for (int n = 0; n < RNN_N; ++n) acc[n] = bias[n];
    #pragma unroll
    for (int q = 0; q < RNN_IN / 4; ++q) {
        const float4 v = u4[q];
        #pragma unroll
        for (int n = 0; n < RNN_N; ++n) {
            const float* wr = W_in + n * RNN_IN + 4 * q;   // uniform -> s_load
            acc[n] = fmaf(wr[0], v.x, acc[n]);
            acc[n] = fmaf(wr[1], v.y, acc[n]);
            acc[n] = fmaf(wr[2], v.z, acc[n]);
            acc[n] = fmaf(wr[3], v.w, acc[n]);
        }
    }
    float4* __restrict__ o4 =
        reinterpret_cast<float4*>(xp) + (size_t)tid * (RNN_N / 4);
    #pragma unroll
    for (int q = 0; q < RNN_N / 4; ++q)
        o4[q] = make_float4(acc[4*q+0], acc[4*q+1], acc[4*q+2], acc[4*q+3]);
}

// ---------------------------------------------------------------------------
// Row-local (16-lane) all-reduce: pure VALU DPP, no LDS pipe, no readlane.
// After 4 stages every lane holds the sum of its 16-lane row.
// ---------------------------------------------------------------------------
template <int CTRL>
__device__ __forceinline__ float dpp_add(float v) {
    int t = __builtin_amdgcn_update_dpp(0, __float_as_int(v), CTRL, 0xf, 0xf, true);
    return v + __int_as_float(t);
}
__device__ __forceinline__ float sum16(float v) {
    v = dpp_add<0xB1>(v);    // quad_perm [1,0,3,2] : xor1
    v = dpp_add<0x4E>(v);    // quad_perm [2,3,0,1] : xor2
    v = dpp_add<0x141>(v);   // row_half_mirror     : cross-quad within 8
    v = dpp_add<0x140>(v);   // row_mirror          : cross-8 within 16
    return v;
}

__device__ __forceinline__ float fast_exp2(float x) {
#if __has_builtin(__builtin_amdgcn_exp2f)
    return __builtin_amdgcn_exp2f(x);
#else
    return __expf(x * 0.6931471805599453f);
#endif
}
__device__ __forceinline__ float fast_rcp(float x) {
#if __has_builtin(__builtin_amdgcn_rcpf)
    return __builtin_amdgcn_rcpf(x);
#else
    return __frcp_rn(x);
#endif
}

// ---------------------------------------------------------------------------
// Kernel 2: sequential scan, one wave per batch. Lane holds the PAIR
// (hA=h[k], hB=h[k+16]), k=lane&15; all four 16-rows replicate. Per step,
// per rank r: fold the pair locally (2 FMA, replaces the xor16 swizzle),
// then 4 row-local DPP adds -> every lane holds S_r in a VGPR. Combine with
// 2*log2(e)-prescaled cM, exp2-based tanh:
//   h' = (0.9h + 0.1) - 0.2 * rcp(exp2(z) + 1),  z = 2*log2e*(x + W h)
// No LDS instructions anywhere in the loop.
// ---------------------------------------------------------------------------
__global__ __launch_bounds__(64, 1) void k_recur(
    const float* __restrict__ m, const float* __restrict__ nvec,
    const float* __restrict__ Mmat, const float* __restrict__ Nmat,
    float* __restrict__ dout, float* __restrict__ hfin)
{
    const int b    = blockIdx.x;
    const int lane = threadIdx.x;
    const int k    = lane & 15;          // pair (k, k+16)
    const int kB   = k + 16;

    // Right factors (pre-reduction), both halves of the pair:
    float cNA[RNN_R + 1], cNB[RNN_R + 1];
    cNA[0] = nvec[k];  cNB[0] = nvec[kB];
    #pragma unroll
    for (int r = 0; r < RNN_R; ++r) { cNA[r+1] = Mmat ? Nmat[k*RNN_R + r] : 0.f; cNB[r+1] = Nmat[kB*RNN_R + r]; }
    // Left factors (post-reduction), prescaled by 2*log2(e):
    float cMA[RNN_R + 1], cMB[RNN_R + 1];
    cMA[0] = KSCALE * m[k];  cMB[0] = KSCALE * m[kB];
    #pragma unroll
    for (int r = 0; r < RNN_R; ++r) { cMA[r+1] = KSCALE * Mmat[k*RNN_R + r]; cMB[r+1] = KSCALE * Mmat[kB*RNN_R + r]; }

    float* __restrict__ base = dout + (size_t)b * (RNN_T * RNN_N);
    float hA = 0.0f, hB = 0.0f;

    const int PF = 4;                    // prefetch ring
    float xrA[PF], xrB[PF];
    #pragma unroll
    for (int i = 0; i < PF; ++i) {
        xrA[i] = base[i * RNN_N + k];
        xrB[i] = base[i * RNN_N + kB];
    }

    #pragma unroll 4
    for (int t = 0; t < RNN_T; ++t) {
        const float xA = xrA[0], xB = xrB[0];
        xrA[0] = xrA[1]; xrA[1] = xrA[2]; xrA[2] = xrA[3];
        xrB[0] = xrB[1]; xrB[1] = xrB[2]; xrB[2] = xrB[3];
        // Unconditional prefetch (reads past T land in allocated space; unused).
        xrA[PF - 1] = base[(t + PF) * RNN_N + k];
        xrB[PF - 1] = base[(t + PF) * RNN_N + kB];

        // 7 reductions: local pair-fold + 4 DPP stages, all-VALU.
        float s[RNN_R + 1];
        #pragma unroll
        for (int r = 0; r < RNN_R + 1; ++r)
            s[r] = sum16(fmaf(hB, cNB[r], hA * cNA[r]));

        // zX = 2*log2e * (x + sum_r cM[r]*s[r]); two chains each.
        float zA0 = fmaf(cMA[0], s[0], KSCALE * xA);
        float zB0 = fmaf(cMB[0], s[0], KSCALE * xB);
        float zA1 = cMA[1] * s[1];
        float zB1 = cMB[1] * s[1];
        zA0 = fmaf(cMA[2], s[2], zA0);  zB0 = fmaf(cMB[2], s[2], zB0);
        zA1 = fmaf(cMA[3], s[3], zA1);  zB1 = fmaf(cMB[3], s[3], zB1);
        zA0 = fmaf(cMA[4], s[4], zA0);  zB0 = fmaf(cMB[4], s[4], zB0);
        zA1 = fmaf(cMA[5], s[5], zA1);  zB1 = fmaf(cMB[5], s[5], zB1);
        zA0 = fmaf(cMA[6], s[6], zA0);  zB0 = fmaf(cMB[6], s[6], zB0);
        const float zA = zA0 + zA1, zB = zB0 + zB1;

        // tanh via exp2: h' = (0.9h + 0.1) - 0.2*rcp(exp2(z)+1)
        const float eA = fast_exp2(zA), eB = fast_exp2(zB);
        const float gA = fmaf(1.0f - RNN_ALPHA, hA, RNN_ALPHA);
        const float gB = fmaf(1.0f - RNN_ALPHA, hB, RNN_ALPHA);
        hA = fmaf(-2.0f * RNN_ALPHA, fast_rcp(eA + 1.0f), gA);
        hB = fmaf(-2.0f * RNN_ALPHA, fast_rcp(eB + 1.0f), gB);

        // Lane l<16 stores hA at col l; lane 16..31 stores hB at col l.
        const float hs = (lane < 16) ? hA : hB;
        if (lane < RNN_N) base[t * RNN_N + lane] = hs;
    }
    const float hs = (lane < 16) ? hA : hB;
    if (lane < RNN_N) hfin[b * RNN_N + lane] = hs;
}

// ---------------------------------------------------------------------------
// Kernel 3: in-place output projection, chunked reads (no big register array).
// ---------------------------------------------------------------------------
__global__ __launch_bounds__(256) void k_out(
    const float* __restrict__ W_out, const float* __restrict__ b_out,
    float* __restrict__ dout)
{
    const int tid = blockIdx.x * 256 + threadIdx.x;   // = b*T + t
    float4* __restrict__ p4 =
        reinterpret_cast<float4*>(dout) + (size_t)tid * (RNN_N / 4);
    float y[RNN_O];
    #pragma unroll
    for (int o = 0; o < RNN_O; ++o) y[o] = b_out[o];
    #pragma unroll
    for (int q = 0; q < RNN_N / 4; ++q) {
        const float4 v = p4[q];
        #pragma unroll
        for (int o = 0; o < RNN_O; ++o) {
            const float* wr = W_out + o * RNN_N + 4 * q;  // uniform -> s_load
            y[o] = fmaf(wr[0], v.x, y[o]);
            y[o] = fmaf(wr[1], v.y, y[o]);
            y[o] = fmaf(wr[2], v.z, y[o]);
            y[o] = fmaf(wr[3], v.w, y[o]);
        }
    }
    #pragma unroll
    for (int q = 0; q < RNN_N / 4; ++q)
        p4[q] = make_float4(y[4*q+0], y[4*q+1], y[4*q+2], y[4*q+3]);
}

extern "C" void kernel_launch(void* const* d_in, const int* in_sizes, int n_in,
                              void* d_out, int out_size, void* d_ws, size_t ws_size,
                              hipStream_t stream)
{
    const float* u     = (const float*)d_in[0];  // [256,2048,64]
    const float* W_in  = (const float*)d_in[1];  // [32,64]
    const float* m     = (const float*)d_in[2];  // [32,1]
    const float* nvec  = (const float*)d_in[3];  // [32,1]
    const float* Mmat  = (const float*)d_in[4];  // [32,6]
    const float* Nmat  = (const float*)d_in[5];  // [32,6]
    const float* bias  = (const float*)d_in[6];  // [32]
    const float* W_out = (const float*)d_in[7];  // [32,32]
    const float* b_out = (const float*)d_in[8];  // [32]
    float* out = (float*)d_out;                  // outputs [256,2048,32] ++ h_final [256,32]

    float* hfin = out + (size_t)RNN_B * RNN_T * RNN_N;

    k_xproj<<<(RNN_B * RNN_T) / 256, 256, 0, stream>>>(u, W_in, bias, out);
    k_recur<<<RNN_B, 64, 0, stream>>>(m, nvec, Mmat, Nmat, out, hfin);
    k_out  <<<(RNN_B * RNN_T) / 256, 256, 0, stream>>>(W_out, b_out, out);
}